// Round 1
// baseline (374.241 us; speedup 1.0000x reference)
//
#include <hip/hip_runtime.h>

// PackedAvgPool1d over ragged packed sequences.
// x: [total_tokens, 768] fp32; seq_lens: [B] int32; kernel_size, stride: scalar int.
// out: [total_y, 768] fp32, total_y = sum(ceil_div(max(L-K,0),S)+1 for L>0).
//
// Memory-bound: each input row read exactly once (K==S==2 windows don't overlap),
// each output row written once. float4 vectorized, coalesced along the 768-dim.
// Ragged layout (x_cu / y_cu prefix sums over the 32 sequences) is recomputed
// per block in LDS (32-iteration serial scan by thread 0, amortized over a
// grid-stride loop). Row -> batch via binary search on y_cu (33 entries, LDS).

#define DIM   768
#define D4    (DIM / 4)   // 192 float4 per row
#define MAXB  128         // supports up to 128 sequences

__global__ __launch_bounds__(256) void packed_avgpool_kernel(
    const float4* __restrict__ x,
    const int*    __restrict__ seq_lens,
    const int*    __restrict__ kptr,
    const int*    __restrict__ sptr,
    float4*       __restrict__ out,
    int batch, long long n4)
{
    __shared__ int s_xcu[MAXB + 1];   // token prefix sums
    __shared__ int s_ycu[MAXB + 1];   // output-row prefix sums
    __shared__ int s_len[MAXB];

    const int K = kptr[0];
    const int S = sptr[0];

    if (threadIdx.x == 0) {
        int xc = 0, yc = 0;
        s_xcu[0] = 0;
        s_ycu[0] = 0;
        for (int i = 0; i < batch; ++i) {
            int L = seq_lens[i];
            s_len[i] = L;
            xc += L;
            int over = (L > K) ? (L - K) : 0;
            int yl = (L == 0) ? 0 : (over + S - 1) / S + 1;   // ceil_div(max(L-K,0),S)+1
            yc += yl;
            s_xcu[i + 1] = xc;
            s_ycu[i + 1] = yc;
        }
    }
    __syncthreads();

    const long long gstride = (long long)gridDim.x * blockDim.x;
    for (long long e = (long long)blockIdx.x * blockDim.x + threadIdx.x;
         e < n4; e += gstride) {
        int row = (int)(e / D4);
        int col = (int)(e - (long long)row * D4);

        // largest b with s_ycu[b] <= row  (y_cu monotone nondecreasing; rows with
        // y_len==0 contribute no row indices so any tie resolves to a valid b)
        int lo = 0, hi = batch - 1;
        while (lo < hi) {
            int mid = (lo + hi + 1) >> 1;
            if (s_ycu[mid] <= row) lo = mid; else hi = mid - 1;
        }
        const int b = lo;
        const int j = row - s_ycu[b];
        const int L = s_len[b];
        const long long base = (long long)s_xcu[b];

        float4 acc = make_float4(0.f, 0.f, 0.f, 0.f);
        int cnt = 0;
        const int p0 = j * S;
        #pragma unroll 4
        for (int k = 0; k < K; ++k) {
            int pos = p0 + k;
            if (pos < L) {
                float4 v = x[(base + pos) * D4 + col];
                acc.x += v.x; acc.y += v.y; acc.z += v.z; acc.w += v.w;
                ++cnt;
            }
        }
        const float inv = 1.0f / (float)cnt;   // cnt in {1..K}; for K=2 exact (1.0 / 0.5)
        acc.x *= inv; acc.y *= inv; acc.z *= inv; acc.w *= inv;
        out[e] = acc;
    }
}

extern "C" void kernel_launch(void* const* d_in, const int* in_sizes, int n_in,
                              void* d_out, int out_size, void* d_ws, size_t ws_size,
                              hipStream_t stream) {
    const float* x        = (const float*)d_in[0];
    const int*   seq_lens = (const int*)d_in[1];
    const int*   kptr     = (const int*)d_in[2];
    const int*   sptr     = (const int*)d_in[3];
    float*       out      = (float*)d_out;

    const int batch = in_sizes[1];
    const long long n4 = (long long)out_size / 4;   // DIM=768 divisible by 4

    // Grid-stride: 4096 blocks (16/CU) so each block amortizes its LDS prefix
    // scan over ~1900 float4 iterations.
    int blocks = 4096;
    long long need = (n4 + 255) / 256;
    if (need < blocks) blocks = (int)(need > 0 ? need : 1);

    packed_avgpool_kernel<<<blocks, 256, 0, stream>>>(
        (const float4*)x, seq_lens, kptr, sptr, (float4*)out, batch, n4);
}

// Round 3
// 372.385 us; speedup vs baseline: 1.0050x; 1.0050x over previous
//
#include <hip/hip_runtime.h>

// PackedAvgPool1d over ragged packed sequences (K=2, S=2 in the bench; code is
// generic in K,S for batch <= 64).
//
// One block per output row (grid.x = total_y = out_size/768, block = 192
// threads = 768/4 float4 lanes). Wave 0 recomputes the ragged prefix sums in
// registers via a 6-step shfl_up scan (seq_lens is 128 B, L2-hot), locates the
// owning sequence with one ballot+popcount, and broadcasts {x_base, window
// start, seq_len} through LDS. No integer division, no binary search.
//
// All global traffic is streaming and coalesced: each input row read exactly
// once (K==S), each output row written once -> ~373 MB total, HBM-bound.
// Invalid taps clamp to pos L-1 (same cache line as a valid tap -> L1 hit) and
// are masked by a 0/1 multiplier, matching the reference's masked average.

#define DIM 768
#define D4  (DIM / 4)   // 192 float4 per row

// clang-native vector for __builtin_nontemporal_store (HIP float4 is a class)
typedef float vfloat4 __attribute__((ext_vector_type(4)));

__global__ __launch_bounds__(D4) void packed_avgpool_rows(
    const float4* __restrict__ x,
    const int*    __restrict__ seq_lens,
    const int*    __restrict__ kptr,
    const int*    __restrict__ sptr,
    float4*       __restrict__ out,
    int batch)
{
    __shared__ int s_base;   // x_cu[b]  (token offset of owning sequence)
    __shared__ int s_p0;     // j * S    (window start within the sequence)
    __shared__ int s_L;      // seq_lens[b]
    __shared__ int s_K;

    const int row = blockIdx.x;

    if (threadIdx.x < 64) {              // wave 0 only (batch <= 64)
        const int lane = threadIdx.x;
        const int K = kptr[0];
        const int S = sptr[0];
        int L = (lane < batch) ? seq_lens[lane] : 0;
        int over = (L > K) ? (L - K) : 0;
        int yl   = (L == 0) ? 0 : (over + S - 1) / S + 1;  // ceil_div(max(L-K,0),S)+1

        // inclusive prefix scan over 64 lanes (tokens xs, output rows ys)
        int xs = L, ys = yl;
        #pragma unroll
        for (int off = 1; off < 64; off <<= 1) {
            int xv = __shfl_up(xs, off);
            int yv = __shfl_up(ys, off);
            if (lane >= off) { xs += xv; ys += yv; }
        }

        // owning sequence: b = #{t : inclusive_ys[t] <= row}
        unsigned long long bal = __ballot(ys <= row);
        int b   = (int)__popcll(bal);
        int xcu = (b == 0) ? 0 : __shfl(xs, b - 1);   // exclusive prefixes
        int ycu = (b == 0) ? 0 : __shfl(ys, b - 1);
        int Lb  = __shfl(L, b);
        if (lane == 0) {
            s_base = xcu;
            s_p0   = (row - ycu) * S;
            s_L    = Lb;
            s_K    = K;
        }
    }
    __syncthreads();

    const int K    = s_K;
    const int L    = s_L;
    const int p0   = s_p0;
    const int base = s_base;
    const int col  = threadIdx.x;

    float4 acc = make_float4(0.f, 0.f, 0.f, 0.f);
    float  cnt = 0.f;
    for (int k = 0; k < K; ++k) {
        int   pos  = p0 + k;
        int   cpos = (pos < L) ? pos : (L - 1);      // clamp: dup line, L1 hit
        float m    = (pos < L) ? 1.f : 0.f;
        float4 v = x[(long long)(base + cpos) * D4 + col];
        acc.x += m * v.x; acc.y += m * v.y; acc.z += m * v.z; acc.w += m * v.w;
        cnt   += m;
    }
    const float inv = 1.0f / cnt;                    // cnt in {1,2} for K=2: exact
    vfloat4 r = { acc.x * inv, acc.y * inv, acc.z * inv, acc.w * inv };
    __builtin_nontemporal_store(
        r, (vfloat4*)&out[(long long)row * D4 + col]);
}

extern "C" void kernel_launch(void* const* d_in, const int* in_sizes, int n_in,
                              void* d_out, int out_size, void* d_ws, size_t ws_size,
                              hipStream_t stream) {
    const float4* x        = (const float4*)d_in[0];
    const int*    seq_lens = (const int*)d_in[1];
    const int*    kptr     = (const int*)d_in[2];
    const int*    sptr     = (const int*)d_in[3];
    float4*       out      = (float4*)d_out;

    const int batch   = in_sizes[1];
    const int total_y = out_size / DIM;   // one block per output row

    packed_avgpool_rows<<<total_y, D4, 0, stream>>>(
        x, seq_lens, kptr, sptr, out, batch);
}